// Round 1
// baseline (37.984 us; speedup 1.0000x reference)
//
#include <hip/hip_runtime.h>

#define AGENT_THRESH 0.5f
#define X_DIS_THRESH 1.5f
#define Y_DIS_THRESH 3.0f
#define DIS2_THRESH  9.0f
#define LOSS_WEIGHT  1.0f

constexpr int B = 128, A = 2048, M = 6, T = 12, C = 10;
constexpr int APB = 256;            // agents per block
constexpr int CHUNKS = A / APB;     // 8
constexpr unsigned int FLT_BIG_BITS = 0x7f7fffffu;  // +FLT_MAX bit pattern

__global__ void init_mins_kernel(unsigned int* __restrict__ mins, int n) {
    int i = blockIdx.x * blockDim.x + threadIdx.x;
    if (i < n) mins[i] = FLT_BIG_BITS;
}

__global__ __launch_bounds__(APB) void plan_coll_main_kernel(
    const float* __restrict__ ego,          // [B,T,2]
    const float* __restrict__ agent_preds,  // [B,A,2]
    const float* __restrict__ afp,          // [B,A,M,T,2]
    const float* __restrict__ scores,       // [B,A,C]
    const float* __restrict__ cls,          // [B,A,M]
    unsigned int* __restrict__ mins)        // [B,T,2] float bits
{
    const int b     = blockIdx.x / CHUNKS;
    const int chunk = blockIdx.x % CHUNKS;
    const int a     = chunk * APB + threadIdx.x;

    __shared__ float predx[T], predy[T];
    __shared__ unsigned int smin[T * 2];

    if (threadIdx.x == 0) {
        float cx = 0.f, cy = 0.f;
        for (int t = 0; t < T; ++t) {
            cx += ego[((size_t)b * T + t) * 2 + 0];
            cy += ego[((size_t)b * T + t) * 2 + 1];
            predx[t] = cx;
            predy[t] = cy;
        }
    }
    if (threadIdx.x < T * 2) smin[threadIdx.x] = FLT_BIG_BITS;
    __syncthreads();

    const size_t ba = (size_t)b * A + a;

    // --- score argmax / validity (first-occurrence argmax like jnp) -------
    const float* sp = scores + ba * C;
    float ms = sp[0];
    int   mi = 0;
    #pragma unroll
    for (int c = 1; c < C; ++c) {
        float v = sp[c];
        if (v > ms) { ms = v; mi = c; }
    }
    const bool valid = (ms >= AGENT_THRESH) && (mi <= 4);

    if (valid) {
        // --- best mode -----------------------------------------------------
        const float* cp = cls + ba * M;
        float mc = cp[0];
        int   mm = 0;
        #pragma unroll
        for (int m = 1; m < M; ++m) {
            float v = cp[m];
            if (v > mc) { mc = v; mm = m; }
        }

        // --- gather selected-mode deltas (24 floats, 16B-aligned) ---------
        const float4* fp = (const float4*)(afp + (ba * M + mm) * (size_t)(T * 2));
        float4 f0 = fp[0], f1 = fp[1], f2 = fp[2], f3 = fp[3], f4 = fp[4], f5 = fp[5];
        float dxv[T * 2];
        dxv[0]=f0.x; dxv[1]=f0.y; dxv[2]=f0.z; dxv[3]=f0.w;
        dxv[4]=f1.x; dxv[5]=f1.y; dxv[6]=f1.z; dxv[7]=f1.w;
        dxv[8]=f2.x; dxv[9]=f2.y; dxv[10]=f2.z; dxv[11]=f2.w;
        dxv[12]=f3.x; dxv[13]=f3.y; dxv[14]=f3.z; dxv[15]=f3.w;
        dxv[16]=f4.x; dxv[17]=f4.y; dxv[18]=f4.z; dxv[19]=f4.w;
        dxv[20]=f5.x; dxv[21]=f5.y; dxv[22]=f5.z; dxv[23]=f5.w;

        const float ax = agent_preds[ba * 2 + 0];
        const float ay = agent_preds[ba * 2 + 1];

        float csx = 0.f, csy = 0.f;
        #pragma unroll
        for (int t = 0; t < T; ++t) {
            csx += dxv[t * 2 + 0];
            csy += dxv[t * 2 + 1];
            const float tx = ax + csx;
            const float ty = ay + csy;
            const float dx = predx[t] - tx;
            const float dy = predy[t] - ty;
            if (dx * dx + dy * dy <= DIS2_THRESH) {
                atomicMin(&smin[t * 2 + 0], __float_as_uint(fabsf(dx)));
                atomicMin(&smin[t * 2 + 1], __float_as_uint(fabsf(dy)));
            }
        }
    }

    __syncthreads();
    if (threadIdx.x < T * 2) {
        unsigned int v = smin[threadIdx.x];
        if (v != FLT_BIG_BITS)
            atomicMin(&mins[(size_t)b * T * 2 + threadIdx.x], v);
    }
}

__global__ __launch_bounds__(256) void finalize_kernel(
    const unsigned int* __restrict__ mins, float* __restrict__ out)
{
    float s = 0.f;
    for (int i = threadIdx.x; i < B * T; i += 256) {
        float xm = __uint_as_float(mins[i * 2 + 0]);
        float ym = __uint_as_float(mins[i * 2 + 1]);
        float xl = (xm > X_DIS_THRESH) ? 0.f : (X_DIS_THRESH - xm);
        float yl = (ym > Y_DIS_THRESH) ? 0.f : (Y_DIS_THRESH - ym);
        s += xl + yl;
    }
    #pragma unroll
    for (int off = 32; off > 0; off >>= 1) s += __shfl_down(s, off, 64);
    __shared__ float wsum[4];
    const int wid = threadIdx.x >> 6;
    if ((threadIdx.x & 63) == 0) wsum[wid] = s;
    __syncthreads();
    if (threadIdx.x == 0) {
        float tot = wsum[0] + wsum[1] + wsum[2] + wsum[3];
        out[0] = LOSS_WEIGHT * tot / (float)(B * T * 2);
    }
}

extern "C" void kernel_launch(void* const* d_in, const int* in_sizes, int n_in,
                              void* d_out, int out_size, void* d_ws, size_t ws_size,
                              hipStream_t stream) {
    const float* ego         = (const float*)d_in[0];  // [B,T,2]
    const float* agent_preds = (const float*)d_in[1];  // [B,A,2]
    const float* afp         = (const float*)d_in[2];  // [B,A,M,T,2]
    const float* scores      = (const float*)d_in[3];  // [B,A,C]
    const float* cls         = (const float*)d_in[4];  // [B,A,M]
    float* out               = (float*)d_out;
    unsigned int* mins       = (unsigned int*)d_ws;    // B*T*2 uints = 12 KB

    const int n_mins = B * T * 2;
    init_mins_kernel<<<(n_mins + 255) / 256, 256, 0, stream>>>(mins, n_mins);
    plan_coll_main_kernel<<<B * CHUNKS, APB, 0, stream>>>(
        ego, agent_preds, afp, scores, cls, mins);
    finalize_kernel<<<1, 256, 0, stream>>>(mins, out);
}

// Round 2
// 36.467 us; speedup vs baseline: 1.0416x; 1.0416x over previous
//
#include <hip/hip_runtime.h>

#define AGENT_THRESH 0.5f
#define X_DIS_THRESH 1.5f
#define Y_DIS_THRESH 3.0f
#define DIS2_THRESH  9.0f
#define LOSS_WEIGHT  1.0f

constexpr int B = 128, A = 2048, M = 6, T = 12, C = 10;
constexpr int APB = 256;            // agents per block
constexpr int CHUNKS = A / APB;     // 8 blocks per batch element
constexpr int NBLK = B * CHUNKS;    // 1024
constexpr unsigned int FLT_BIG_BITS = 0x7f7fffffu;  // +FLT_MAX bit pattern

// Kernel 1: per-(b,chunk) block computes 24-slot (t,coord) min over its 256
// agents, writes plain (non-atomic) to blockmins[blockIdx][24]. No init pass
// needed: every slot is written unconditionally.
__global__ __launch_bounds__(APB) void plan_coll_main_kernel(
    const float* __restrict__ ego,          // [B,T,2]
    const float* __restrict__ agent_preds,  // [B,A,2]
    const float* __restrict__ afp,          // [B,A,M,T,2]
    const float* __restrict__ scores,       // [B,A,C]
    const float* __restrict__ cls,          // [B,A,M]
    unsigned int* __restrict__ blockmins)   // [NBLK, 24] float bits
{
    const int b     = blockIdx.x / CHUNKS;
    const int chunk = blockIdx.x % CHUNKS;
    const int a     = chunk * APB + threadIdx.x;

    __shared__ float predx[T], predy[T];
    __shared__ unsigned int smin[T * 2];

    if (threadIdx.x == 0) {
        float cx = 0.f, cy = 0.f;
        #pragma unroll
        for (int t = 0; t < T; ++t) {
            cx += ego[((size_t)b * T + t) * 2 + 0];
            cy += ego[((size_t)b * T + t) * 2 + 1];
            predx[t] = cx;
            predy[t] = cy;
        }
    }
    if (threadIdx.x < T * 2) smin[threadIdx.x] = FLT_BIG_BITS;
    __syncthreads();

    const size_t ba = (size_t)b * A + a;

    // --- score argmax / validity (first-occurrence argmax like jnp) -------
    const float2* sp2 = (const float2*)(scores + ba * C);   // 8B-aligned
    float sv[C];
    #pragma unroll
    for (int i = 0; i < C / 2; ++i) {
        float2 v = sp2[i];
        sv[2 * i] = v.x; sv[2 * i + 1] = v.y;
    }
    float ms = sv[0];
    int   mi = 0;
    #pragma unroll
    for (int c = 1; c < C; ++c)
        if (sv[c] > ms) { ms = sv[c]; mi = c; }
    const bool valid = (ms >= AGENT_THRESH) && (mi <= 4);

    if (valid) {
        // --- best mode -----------------------------------------------------
        const float2* cp2 = (const float2*)(cls + ba * M);  // 8B-aligned
        float cv[M];
        #pragma unroll
        for (int i = 0; i < M / 2; ++i) {
            float2 v = cp2[i];
            cv[2 * i] = v.x; cv[2 * i + 1] = v.y;
        }
        float mc = cv[0];
        int   mm = 0;
        #pragma unroll
        for (int m = 1; m < M; ++m)
            if (cv[m] > mc) { mc = cv[m]; mm = m; }

        // --- gather selected-mode deltas (24 floats, 16B-aligned) ---------
        const float4* fp = (const float4*)(afp + (ba * M + mm) * (size_t)(T * 2));
        float4 f0 = fp[0], f1 = fp[1], f2 = fp[2], f3 = fp[3], f4 = fp[4], f5 = fp[5];
        float dxv[T * 2];
        dxv[0]=f0.x; dxv[1]=f0.y; dxv[2]=f0.z; dxv[3]=f0.w;
        dxv[4]=f1.x; dxv[5]=f1.y; dxv[6]=f1.z; dxv[7]=f1.w;
        dxv[8]=f2.x; dxv[9]=f2.y; dxv[10]=f2.z; dxv[11]=f2.w;
        dxv[12]=f3.x; dxv[13]=f3.y; dxv[14]=f3.z; dxv[15]=f3.w;
        dxv[16]=f4.x; dxv[17]=f4.y; dxv[18]=f4.z; dxv[19]=f4.w;
        dxv[20]=f5.x; dxv[21]=f5.y; dxv[22]=f5.z; dxv[23]=f5.w;

        const float ax = agent_preds[ba * 2 + 0];
        const float ay = agent_preds[ba * 2 + 1];

        float csx = 0.f, csy = 0.f;
        #pragma unroll
        for (int t = 0; t < T; ++t) {
            csx += dxv[t * 2 + 0];
            csy += dxv[t * 2 + 1];
            const float tx = ax + csx;
            const float ty = ay + csy;
            const float dx = predx[t] - tx;
            const float dy = predy[t] - ty;
            if (dx * dx + dy * dy <= DIS2_THRESH) {
                atomicMin(&smin[t * 2 + 0], __float_as_uint(fabsf(dx)));
                atomicMin(&smin[t * 2 + 1], __float_as_uint(fabsf(dy)));
            }
        }
    }

    __syncthreads();
    if (threadIdx.x < T * 2)
        blockmins[(size_t)blockIdx.x * (T * 2) + threadIdx.x] = smin[threadIdx.x];
}

// Kernel 2: reduce 1024x24 table over the 8 chunks of each b, hinge, mean.
__global__ __launch_bounds__(256) void finalize_kernel(
    const unsigned int* __restrict__ blockmins, float* __restrict__ out)
{
    float s = 0.f;
    for (int slot = threadIdx.x; slot < B * T * 2; slot += 256) {
        const int b  = slot / (T * 2);
        const int sc = slot % (T * 2);
        unsigned int m = blockmins[((size_t)b * CHUNKS + 0) * (T * 2) + sc];
        #pragma unroll
        for (int j = 1; j < CHUNKS; ++j) {
            unsigned int v = blockmins[((size_t)b * CHUNKS + j) * (T * 2) + sc];
            m = (v < m) ? v : m;   // valid: all values are non-negative floats
        }
        const float mv  = __uint_as_float(m);
        const float thr = (sc & 1) ? Y_DIS_THRESH : X_DIS_THRESH;
        s += (mv > thr) ? 0.f : (thr - mv);
    }
    #pragma unroll
    for (int off = 32; off > 0; off >>= 1) s += __shfl_down(s, off, 64);
    __shared__ float wsum[4];
    const int wid = threadIdx.x >> 6;
    if ((threadIdx.x & 63) == 0) wsum[wid] = s;
    __syncthreads();
    if (threadIdx.x == 0) {
        float tot = wsum[0] + wsum[1] + wsum[2] + wsum[3];
        out[0] = LOSS_WEIGHT * tot / (float)(B * T * 2);
    }
}

extern "C" void kernel_launch(void* const* d_in, const int* in_sizes, int n_in,
                              void* d_out, int out_size, void* d_ws, size_t ws_size,
                              hipStream_t stream) {
    const float* ego         = (const float*)d_in[0];  // [B,T,2]
    const float* agent_preds = (const float*)d_in[1];  // [B,A,2]
    const float* afp         = (const float*)d_in[2];  // [B,A,M,T,2]
    const float* scores      = (const float*)d_in[3];  // [B,A,C]
    const float* cls         = (const float*)d_in[4];  // [B,A,M]
    float* out               = (float*)d_out;
    unsigned int* blockmins  = (unsigned int*)d_ws;    // NBLK*24 uints = 96 KB

    plan_coll_main_kernel<<<NBLK, APB, 0, stream>>>(
        ego, agent_preds, afp, scores, cls, blockmins);
    finalize_kernel<<<1, 256, 0, stream>>>(blockmins, out);
}

// Round 3
// 20.137 us; speedup vs baseline: 1.8863x; 1.8109x over previous
//
#include <hip/hip_runtime.h>

#define AGENT_THRESH 0.5f
#define X_DIS_THRESH 1.5f
#define Y_DIS_THRESH 3.0f
#define DIS2_THRESH  9.0f
#define LOSS_WEIGHT  1.0f
#define FLT_BIG      3.402823466e+38f

constexpr int B = 128, A = 2048, M = 6, T = 12, C = 10;
constexpr int APB = 256;            // agents per block
constexpr int CHUNKS = A / APB;     // 8 blocks per batch element
constexpr int NBLK = B * CHUNKS;    // 1024
constexpr int SLOTS = T * 2;        // 24
constexpr int GRP = 10;             // reducer threads per slot (240 active)

// Kernel 1: per-(b,chunk) block computes 24-slot (t,coord) min over its 256
// agents. Per-thread register mins (branchless), then LDS transpose-reduce
// (no atomics). Writes plain to blockmins[blockIdx][24].
__global__ __launch_bounds__(APB) void pcl_main_kernel(
    const float* __restrict__ ego,          // [B,T,2]
    const float* __restrict__ agent_preds,  // [B,A,2]
    const float* __restrict__ afp,          // [B,A,M,T,2]
    const float* __restrict__ scores,       // [B,A,C]
    const float* __restrict__ cls,          // [B,A,M]
    float* __restrict__ blockmins)          // [NBLK, 24]
{
    const int b     = blockIdx.x / CHUNKS;
    const int chunk = blockIdx.x % CHUNKS;
    const int tid   = threadIdx.x;
    const int a     = chunk * APB + tid;

    __shared__ float egoraw[SLOTS];
    __shared__ float predx[T], predy[T];
    __shared__ float sred[APB][25];         // pad 25: (tid*25)%32 covers all banks
    __shared__ float spart[SLOTS * GRP];    // 240 partials

    const size_t ba = (size_t)b * A + a;

    // --- issue all independent global loads up front ----------------------
    const float2* sp2 = (const float2*)(scores + ba * C);
    float2 s0 = sp2[0], s1 = sp2[1], s2 = sp2[2], s3 = sp2[3], s4 = sp2[4];
    const float2* cp2 = (const float2*)(cls + ba * M);
    float2 c0 = cp2[0], c1 = cp2[1], c2 = cp2[2];
    const float2 apxy = ((const float2*)agent_preds)[ba];

    if (tid < SLOTS) egoraw[tid] = ego[(size_t)b * SLOTS + tid];
    __syncthreads();
    if (tid == 0) {
        float cx = 0.f, cy = 0.f;
        #pragma unroll
        for (int t = 0; t < T; ++t) {
            cx += egoraw[2 * t + 0];
            cy += egoraw[2 * t + 1];
            predx[t] = cx;
            predy[t] = cy;
        }
    }
    __syncthreads();

    // --- score argmax / validity (first-occurrence argmax like jnp) -------
    float sv[C] = {s0.x, s0.y, s1.x, s1.y, s2.x, s2.y, s3.x, s3.y, s4.x, s4.y};
    float ms = sv[0];
    int   mi = 0;
    #pragma unroll
    for (int c = 1; c < C; ++c)
        if (sv[c] > ms) { ms = sv[c]; mi = c; }
    const bool valid = (ms >= AGENT_THRESH) && (mi <= 4);

    float p[SLOTS];
    #pragma unroll
    for (int k = 0; k < SLOTS; ++k) p[k] = FLT_BIG;

    if (valid) {
        // --- best mode (loads already in flight) ---------------------------
        float cv[M] = {c0.x, c0.y, c1.x, c1.y, c2.x, c2.y};
        float mc = cv[0];
        int   mm = 0;
        #pragma unroll
        for (int m = 1; m < M; ++m)
            if (cv[m] > mc) { mc = cv[m]; mm = m; }

        // --- gather selected-mode deltas (24 floats, 16B-aligned) ---------
        const float4* fp = (const float4*)(afp + (ba * M + mm) * (size_t)SLOTS);
        float4 f0 = fp[0], f1 = fp[1], f2 = fp[2], f3 = fp[3], f4 = fp[4], f5 = fp[5];
        float dxv[SLOTS];
        dxv[0]=f0.x; dxv[1]=f0.y; dxv[2]=f0.z; dxv[3]=f0.w;
        dxv[4]=f1.x; dxv[5]=f1.y; dxv[6]=f1.z; dxv[7]=f1.w;
        dxv[8]=f2.x; dxv[9]=f2.y; dxv[10]=f2.z; dxv[11]=f2.w;
        dxv[12]=f3.x; dxv[13]=f3.y; dxv[14]=f3.z; dxv[15]=f3.w;
        dxv[16]=f4.x; dxv[17]=f4.y; dxv[18]=f4.z; dxv[19]=f4.w;
        dxv[20]=f5.x; dxv[21]=f5.y; dxv[22]=f5.z; dxv[23]=f5.w;

        float csx = 0.f, csy = 0.f;
        #pragma unroll
        for (int t = 0; t < T; ++t) {
            csx += dxv[2 * t + 0];
            csy += dxv[2 * t + 1];
            const float dx = predx[t] - (apxy.x + csx);
            const float dy = predy[t] - (apxy.y + csy);
            const bool hit = (dx * dx + dy * dy <= DIS2_THRESH);
            p[2 * t + 0] = fminf(p[2 * t + 0], hit ? fabsf(dx) : FLT_BIG);
            p[2 * t + 1] = fminf(p[2 * t + 1], hit ? fabsf(dy) : FLT_BIG);
        }
    }

    // --- transpose-reduce: regs -> LDS, 10 threads per slot ----------------
    #pragma unroll
    for (int k = 0; k < SLOTS; ++k) sred[tid][k] = p[k];
    __syncthreads();

    if (tid < SLOTS * GRP) {
        const int s = tid % SLOTS;
        const int g = tid / SLOTS;
        float pm = FLT_BIG;
        for (int r = g; r < APB; r += GRP) pm = fminf(pm, sred[r][s]);
        spart[tid] = pm;
    }
    __syncthreads();

    if (tid < SLOTS) {
        float m = spart[tid];
        #pragma unroll
        for (int g = 1; g < GRP; ++g) m = fminf(m, spart[g * SLOTS + tid]);
        blockmins[(size_t)blockIdx.x * SLOTS + tid] = m;
    }
}

// Kernel 2: reduce 1024x24 table over the 8 chunks of each b, hinge, mean.
__global__ __launch_bounds__(256) void pcl_finalize_kernel(
    const float* __restrict__ blockmins, float* __restrict__ out)
{
    float s = 0.f;
    for (int slot = threadIdx.x; slot < B * SLOTS; slot += 256) {
        const int b  = slot / SLOTS;
        const int sc = slot % SLOTS;
        float m = blockmins[((size_t)b * CHUNKS + 0) * SLOTS + sc];
        #pragma unroll
        for (int j = 1; j < CHUNKS; ++j)
            m = fminf(m, blockmins[((size_t)b * CHUNKS + j) * SLOTS + sc]);
        const float thr = (sc & 1) ? Y_DIS_THRESH : X_DIS_THRESH;
        s += (m > thr) ? 0.f : (thr - m);
    }
    #pragma unroll
    for (int off = 32; off > 0; off >>= 1) s += __shfl_down(s, off, 64);
    __shared__ float wsum[4];
    const int wid = threadIdx.x >> 6;
    if ((threadIdx.x & 63) == 0) wsum[wid] = s;
    __syncthreads();
    if (threadIdx.x == 0) {
        float tot = wsum[0] + wsum[1] + wsum[2] + wsum[3];
        out[0] = LOSS_WEIGHT * tot / (float)(B * SLOTS);
    }
}

extern "C" void kernel_launch(void* const* d_in, const int* in_sizes, int n_in,
                              void* d_out, int out_size, void* d_ws, size_t ws_size,
                              hipStream_t stream) {
    const float* ego         = (const float*)d_in[0];  // [B,T,2]
    const float* agent_preds = (const float*)d_in[1];  // [B,A,2]
    const float* afp         = (const float*)d_in[2];  // [B,A,M,T,2]
    const float* scores      = (const float*)d_in[3];  // [B,A,C]
    const float* cls         = (const float*)d_in[4];  // [B,A,M]
    float* out               = (float*)d_out;
    float* blockmins         = (float*)d_ws;           // NBLK*24 floats = 96 KB

    pcl_main_kernel<<<NBLK, APB, 0, stream>>>(
        ego, agent_preds, afp, scores, cls, blockmins);
    pcl_finalize_kernel<<<1, 256, 0, stream>>>(blockmins, out);
}

// Round 4
// 20.132 us; speedup vs baseline: 1.8868x; 1.0003x over previous
//
#include <hip/hip_runtime.h>

#define AGENT_THRESH 0.5f
#define X_DIS_THRESH 1.5f
#define Y_DIS_THRESH 3.0f
#define DIS2_THRESH  9.0f
#define LOSS_WEIGHT  1.0f
#define FLT_BIG      3.402823466e+38f

constexpr int B = 128, A = 2048, M = 6, T = 12, C = 10;
constexpr int APB = 128;            // threads per block
constexpr int AGPT = 2;             // agents per thread
constexpr int APBLK = APB * AGPT;   // 256 agents per block
constexpr int CHUNKS = A / APBLK;   // 8 blocks per batch element
constexpr int NBLK = B * CHUNKS;    // 1024
constexpr int SLOTS = T * 2;        // 24
constexpr int GRP = 5;              // reducer threads per slot (120 active)

__device__ __forceinline__ void agent_mins(
    const float sv[C], const float cv[M], float2 apxy,
    const float* __restrict__ afp, size_t ba,
    const float* predx, const float* predy, float p[SLOTS])
{
    float ms = sv[0];
    int   mi = 0;
    #pragma unroll
    for (int c = 1; c < C; ++c)
        if (sv[c] > ms) { ms = sv[c]; mi = c; }
    const bool valid = (ms >= AGENT_THRESH) && (mi <= 4);
    if (!valid) return;

    float mc = cv[0];
    int   mm = 0;
    #pragma unroll
    for (int m = 1; m < M; ++m)
        if (cv[m] > mc) { mc = cv[m]; mm = m; }

    const float4* fp = (const float4*)(afp + (ba * M + mm) * (size_t)SLOTS);
    float4 f0 = fp[0], f1 = fp[1], f2 = fp[2], f3 = fp[3], f4 = fp[4], f5 = fp[5];
    float dxv[SLOTS];
    dxv[0]=f0.x; dxv[1]=f0.y; dxv[2]=f0.z; dxv[3]=f0.w;
    dxv[4]=f1.x; dxv[5]=f1.y; dxv[6]=f1.z; dxv[7]=f1.w;
    dxv[8]=f2.x; dxv[9]=f2.y; dxv[10]=f2.z; dxv[11]=f2.w;
    dxv[12]=f3.x; dxv[13]=f3.y; dxv[14]=f3.z; dxv[15]=f3.w;
    dxv[16]=f4.x; dxv[17]=f4.y; dxv[18]=f4.z; dxv[19]=f4.w;
    dxv[20]=f5.x; dxv[21]=f5.y; dxv[22]=f5.z; dxv[23]=f5.w;

    float csx = 0.f, csy = 0.f;
    #pragma unroll
    for (int t = 0; t < T; ++t) {
        csx += dxv[2 * t + 0];
        csy += dxv[2 * t + 1];
        const float dx = predx[t] - (apxy.x + csx);
        const float dy = predy[t] - (apxy.y + csy);
        const bool hit = (dx * dx + dy * dy <= DIS2_THRESH);
        p[2 * t + 0] = fminf(p[2 * t + 0], hit ? fabsf(dx) : FLT_BIG);
        p[2 * t + 1] = fminf(p[2 * t + 1], hit ? fabsf(dy) : FLT_BIG);
    }
}

// Kernel 1: per-(b,chunk) block computes 24-slot min over its 256 agents,
// 2 agents/thread for doubled memory-level parallelism. No atomics.
__global__ __launch_bounds__(APB) void pcl_main_kernel(
    const float* __restrict__ ego,          // [B,T,2]
    const float* __restrict__ agent_preds,  // [B,A,2]
    const float* __restrict__ afp,          // [B,A,M,T,2]
    const float* __restrict__ scores,       // [B,A,C]
    const float* __restrict__ cls,          // [B,A,M]
    float* __restrict__ blockmins)          // [NBLK, 24]
{
    const int b     = blockIdx.x / CHUNKS;
    const int chunk = blockIdx.x % CHUNKS;
    const int tid   = threadIdx.x;
    const size_t baA = (size_t)b * A + chunk * APBLK + tid;
    const size_t baB = baA + APB;

    __shared__ float egoraw[SLOTS];
    __shared__ float predx[T], predy[T];
    __shared__ float sred[APB][25];         // stride 25 (odd): conflict-benign
    __shared__ float spart[SLOTS * GRP];    // 120 partials

    // --- issue all independent global loads up front ----------------------
    const float2* spA = (const float2*)(scores + baA * C);
    const float2* spB = (const float2*)(scores + baB * C);
    float2 sA0 = spA[0], sA1 = spA[1], sA2 = spA[2], sA3 = spA[3], sA4 = spA[4];
    float2 sB0 = spB[0], sB1 = spB[1], sB2 = spB[2], sB3 = spB[3], sB4 = spB[4];
    const float2* cpA = (const float2*)(cls + baA * M);
    const float2* cpB = (const float2*)(cls + baB * M);
    float2 cA0 = cpA[0], cA1 = cpA[1], cA2 = cpA[2];
    float2 cB0 = cpB[0], cB1 = cpB[1], cB2 = cpB[2];
    const float2 apA = ((const float2*)agent_preds)[baA];
    const float2 apB = ((const float2*)agent_preds)[baB];

    if (tid < SLOTS) egoraw[tid] = ego[(size_t)b * SLOTS + tid];
    __syncthreads();
    if (tid < SLOTS) {
        // thread tid<12 -> predx[tid]; 12..23 -> predy[tid-12]
        const int coord = (tid >= T) ? 1 : 0;
        const int tt    = tid - T * coord;
        float s = 0.f;
        for (int i = 0; i <= tt; ++i) s += egoraw[2 * i + coord];
        if (coord) predy[tt] = s; else predx[tt] = s;
    }
    __syncthreads();

    float p[SLOTS];
    #pragma unroll
    for (int k = 0; k < SLOTS; ++k) p[k] = FLT_BIG;

    {
        const float svA[C] = {sA0.x,sA0.y,sA1.x,sA1.y,sA2.x,sA2.y,sA3.x,sA3.y,sA4.x,sA4.y};
        const float cvA[M] = {cA0.x,cA0.y,cA1.x,cA1.y,cA2.x,cA2.y};
        agent_mins(svA, cvA, apA, afp, baA, predx, predy, p);
    }
    {
        const float svB[C] = {sB0.x,sB0.y,sB1.x,sB1.y,sB2.x,sB2.y,sB3.x,sB3.y,sB4.x,sB4.y};
        const float cvB[M] = {cB0.x,cB0.y,cB1.x,cB1.y,cB2.x,cB2.y};
        agent_mins(svB, cvB, apB, afp, baB, predx, predy, p);
    }

    // --- transpose-reduce: regs -> LDS, GRP threads per slot ---------------
    #pragma unroll
    for (int k = 0; k < SLOTS; ++k) sred[tid][k] = p[k];
    __syncthreads();

    if (tid < SLOTS * GRP) {
        const int s = tid % SLOTS;
        const int g = tid / SLOTS;
        float pm = FLT_BIG;
        for (int r = g; r < APB; r += GRP) pm = fminf(pm, sred[r][s]);
        spart[tid] = pm;
    }
    __syncthreads();

    if (tid < SLOTS) {
        float m = spart[tid];
        #pragma unroll
        for (int g = 1; g < GRP; ++g) m = fminf(m, spart[g * SLOTS + tid]);
        blockmins[(size_t)blockIdx.x * SLOTS + tid] = m;
    }
}

// Kernel 2: reduce 1024x24 table over the 8 chunks of each b, hinge, mean.
__global__ __launch_bounds__(256) void pcl_finalize_kernel(
    const float* __restrict__ blockmins, float* __restrict__ out)
{
    float s = 0.f;
    for (int slot = threadIdx.x; slot < B * SLOTS; slot += 256) {
        const int b  = slot / SLOTS;
        const int sc = slot % SLOTS;
        float m = blockmins[((size_t)b * CHUNKS + 0) * SLOTS + sc];
        #pragma unroll
        for (int j = 1; j < CHUNKS; ++j)
            m = fminf(m, blockmins[((size_t)b * CHUNKS + j) * SLOTS + sc]);
        const float thr = (sc & 1) ? Y_DIS_THRESH : X_DIS_THRESH;
        s += (m > thr) ? 0.f : (thr - m);
    }
    #pragma unroll
    for (int off = 32; off > 0; off >>= 1) s += __shfl_down(s, off, 64);
    __shared__ float wsum[4];
    const int wid = threadIdx.x >> 6;
    if ((threadIdx.x & 63) == 0) wsum[wid] = s;
    __syncthreads();
    if (threadIdx.x == 0) {
        float tot = wsum[0] + wsum[1] + wsum[2] + wsum[3];
        out[0] = LOSS_WEIGHT * tot / (float)(B * SLOTS);
    }
}

extern "C" void kernel_launch(void* const* d_in, const int* in_sizes, int n_in,
                              void* d_out, int out_size, void* d_ws, size_t ws_size,
                              hipStream_t stream) {
    const float* ego         = (const float*)d_in[0];  // [B,T,2]
    const float* agent_preds = (const float*)d_in[1];  // [B,A,2]
    const float* afp         = (const float*)d_in[2];  // [B,A,M,T,2]
    const float* scores      = (const float*)d_in[3];  // [B,A,C]
    const float* cls         = (const float*)d_in[4];  // [B,A,M]
    float* out               = (float*)d_out;
    float* blockmins         = (float*)d_ws;           // NBLK*24 floats = 96 KB

    pcl_main_kernel<<<NBLK, APB, 0, stream>>>(
        ego, agent_preds, afp, scores, cls, blockmins);
    pcl_finalize_kernel<<<1, 256, 0, stream>>>(blockmins, out);
}